// Round 4
// baseline (403.697 us; speedup 1.0000x reference)
//
#include <hip/hip_runtime.h>

#define N_NODES 262144
#define BM 32
#define NTHREADS 256

typedef short s16x8 __attribute__((ext_vector_type(8)));
typedef float f32x4 __attribute__((ext_vector_type(4)));

static __device__ __forceinline__ unsigned short f2bf(float f) {
  union { float f; unsigned u; } v; v.f = f;
  unsigned u = v.u;
  u += 0x7FFFu + ((u >> 16) & 1u);   // round-to-nearest-even
  return (unsigned short)(u >> 16);
}

static __device__ __forceinline__ unsigned long long pack4bf(f32x4 v) {
  unsigned u0 = (unsigned)f2bf(v.x) | ((unsigned)f2bf(v.y) << 16);
  unsigned u1 = (unsigned)f2bf(v.z) | ((unsigned)f2bf(v.w) << 16);
  return (unsigned long long)u0 | ((unsigned long long)u1 << 32);
}

static __device__ __forceinline__ float fsig(float x) {
  return __builtin_amdgcn_rcpf(1.0f + __expf(-x));
}
static __device__ __forceinline__ float ftanh(float x) {
  return 2.0f * __builtin_amdgcn_rcpf(1.0f + __expf(-2.0f * x)) - 1.0f;
}

// Weight prep:
//  Wh2[kb][n][ki] (16 x 64 x 32 bf16)  = W_hid[n][kb*32+ki]
//  W2 [kb][n][ki] ( 8 x 512 x 32 bf16) = k<128 ? W_ih[n][k] : W_hh[n][k-128]
//  biasg[512] = b_ih + b_hh
__global__ void prep_kernel(const float* __restrict__ Whid, const float* __restrict__ Wih,
                            const float* __restrict__ Whh, const float* __restrict__ bih,
                            const float* __restrict__ bhh,
                            unsigned short* __restrict__ oWh2, unsigned short* __restrict__ oW2,
                            float* __restrict__ oBias) {
  int t = blockIdx.x * 256 + threadIdx.x;
  if (t < 32768) {
    int kb = t >> 11, n = (t >> 5) & 63, ki = t & 31;
    oWh2[t] = f2bf(Whid[n * 512 + kb * 32 + ki]);
  }
  if (t < 131072) {
    int kb = t >> 14, n = (t >> 5) & 511, ki = t & 31;
    int k = kb * 32 + ki;
    float v = (k < 128) ? Wih[n * 128 + k] : Whh[n * 128 + (k - 128)];
    oW2[t] = f2bf(v);
  }
  if (t < 512) oBias[t] = bih[t] + bhh[t];
}

// All LDS tiles are 32 rows x 256 bf16 (512B rows). XOR-swizzle spreads the
// 16-row-strided b128 column reads across 8 16B slots (G4).
#define SWZ(m, b) ((((m) * 512) + (b)) ^ (((m) & 7) << 4))

__global__ __launch_bounds__(NTHREADS, 4) void node_rnn_kernel(
    const float* __restrict__ Hv, const float* __restrict__ hvv,
    const float* __restrict__ xv, const float* __restrict__ hvp,
    const float* __restrict__ cvp, const int* __restrict__ tsm,
    const float* __restrict__ Wpos, const float* __restrict__ bpos,
    const float* __restrict__ bhid,
    const unsigned short* __restrict__ Wh2,
    const unsigned short* __restrict__ W2,
    const float* __restrict__ biasg,
    float* __restrict__ hvo, float* __restrict__ cvo)
{
  __shared__ __align__(16) char lds[32768];   // buf0 = lds, buf1 = lds+16384
  char* buf0 = lds;
  char* buf1 = lds + 16384;

  const int tid = threadIdx.x;
  const int w   = tid >> 6;      // wave 0..3
  const int l   = tid & 63;
  const int l15 = l & 15;
  const int lk  = l >> 4;        // k-group 0..3
  const int node0 = blockIdx.x * BM;

  // ---- Stage half 0 (hvv, K 0..255) -> buf0: coalesced f32x4, bf16-convert once
#pragma unroll
  for (int it = 0; it < 8; ++it) {
    int p = tid + it * NTHREADS;            // 32 rows x 64 f32x4-chunks
    int m = p >> 6, ch = p & 63;
    f32x4 v = *(const f32x4*)(hvv + (size_t)(node0 + m) * 256 + ch * 4);
    *(unsigned long long*)(buf0 + SWZ(m, ch * 8)) = pack4bf(v);
  }

  // ---- T14 async-stage: issue half-1 (Hv) loads now, write to buf1 after mfma-h0
  f32x4 gv[8];
#pragma unroll
  for (int it = 0; it < 8; ++it) {
    int p = tid + it * NTHREADS;
    int m = p >> 6, ch = p & 63;
    gv[it] = *(const f32x4*)(Hv + (size_t)(node0 + m) * 256 + ch * 4);
  }

  // ---- e_v = relu(xv @ Wpos^T + bpos) into regs
  float ev[8];
#pragma unroll
  for (int it = 0; it < 8; ++it) {
    int p = tid + it * NTHREADS;            // 32 rows x 64 cols
    int m = p >> 6, j = p & 63;
    float x0 = xv[(size_t)(node0 + m) * 2 + 0];
    float x1 = xv[(size_t)(node0 + m) * 2 + 1];
    ev[it] = fmaxf(x0 * Wpos[j * 2 + 0] + x1 * Wpos[j * 2 + 1] + bpos[j], 0.0f);
  }
  // ---- hv_tm1 prefetch into regs
  f32x4 hvc[4];
#pragma unroll
  for (int it = 0; it < 4; ++it) {
    int p = tid + it * NTHREADS;            // 32 rows x 32 f32x4-chunks
    int m = p >> 5, c4 = p & 31;
    hvc[it] = *(const f32x4*)(hvp + (size_t)(node0 + m) * 128 + c4 * 4);
  }

  __syncthreads();   // B1: buf0 staged

  // ---- Phase 1a: acc += buf0 @ Wh^T (K 0..255). Wave w: cols [16w,16w+16), rows all 32.
  f32x4 acc[2] = {f32x4{0.f,0.f,0.f,0.f}, f32x4{0.f,0.f,0.f,0.f}};
  const char* whb = (const char*)Wh2 + (16 * w + l15) * 64 + lk * 16;
#pragma unroll
  for (int ks = 0; ks < 8; ++ks) {
    s16x8 bf = *(const s16x8*)(whb + ks * 4096);
#pragma unroll
    for (int mi = 0; mi < 2; ++mi) {
      s16x8 af = *(const s16x8*)(buf0 + SWZ(mi * 16 + l15, ks * 64 + lk * 16));
      acc[mi] = __builtin_amdgcn_mfma_f32_16x16x32_bf16(af, bf, acc[mi], 0, 0, 0);
    }
  }

  // ---- write staged half 1 -> buf1 (overlaps mfma-h0 within the B1..B2 region)
#pragma unroll
  for (int it = 0; it < 8; ++it) {
    int p = tid + it * NTHREADS;
    int m = p >> 6, ch = p & 63;
    *(unsigned long long*)(buf1 + SWZ(m, ch * 8)) = pack4bf(gv[it]);
  }

  __syncthreads();   // B2: buf1 staged AND all buf0 (h0) reads done

  // ---- Phase 1b: acc += buf1 @ Wh^T (K 256..511)
#pragma unroll
  for (int ks = 0; ks < 8; ++ks) {
    s16x8 bf = *(const s16x8*)(whb + (8 + ks) * 4096);
#pragma unroll
    for (int mi = 0; mi < 2; ++mi) {
      s16x8 af = *(const s16x8*)(buf1 + SWZ(mi * 16 + l15, ks * 64 + lk * 16));
      acc[mi] = __builtin_amdgcn_mfma_f32_16x16x32_bf16(af, bf, acc[mi], 0, 0, 0);
    }
  }

  // ---- Build A2 = [e_v(64) | a_v(64) | hv(128)] bf16 in buf0 (overlaps mfma-h1)
#pragma unroll
  for (int it = 0; it < 8; ++it) {
    int p = tid + it * NTHREADS;
    int m = p >> 6, j = p & 63;
    *(unsigned short*)(buf0 + SWZ(m, j * 2)) = f2bf(ev[it]);
  }
#pragma unroll
  for (int it = 0; it < 4; ++it) {
    int p = tid + it * NTHREADS;
    int m = p >> 5, c4 = p & 31;
    *(unsigned long long*)(buf0 + SWZ(m, 256 + c4 * 8)) = pack4bf(hvc[it]);
  }
  {
    float bb = bhid[16 * w + l15];
    int cb = (64 + 16 * w + l15) * 2;
#pragma unroll
    for (int mi = 0; mi < 2; ++mi) {
#pragma unroll
      for (int r = 0; r < 4; ++r) {
        int m = mi * 16 + lk * 4 + r;
        float av = fmaxf(acc[mi][r] + bb, 0.0f);
        *(unsigned short*)(buf0 + SWZ(m, cb)) = f2bf(av);
      }
    }
  }
  __syncthreads();   // B3: A2 complete

  // ---- Phase 2: gates = A2(32x256) @ [Wih;Whh]^T.
  // Wave w owns d-slices {16w, 16w+64} of every gate: n = 128*j + 64*h + 16*w + l15.
  f32x4 acc2[2][4][2];
#pragma unroll
  for (int mi = 0; mi < 2; ++mi)
#pragma unroll
    for (int j = 0; j < 4; ++j)
#pragma unroll
      for (int h = 0; h < 2; ++h) acc2[mi][j][h] = f32x4{0.f,0.f,0.f,0.f};

#pragma unroll
  for (int kk = 0; kk < 8; ++kk) {
    s16x8 a[2];
#pragma unroll
    for (int mi = 0; mi < 2; ++mi)
      a[mi] = *(const s16x8*)(buf0 + SWZ(mi * 16 + l15, kk * 64 + lk * 16));
    const char* wb = (const char*)W2 + kk * 32768 + (16 * w + l15) * 64 + lk * 16;
#pragma unroll
    for (int j = 0; j < 4; ++j) {
#pragma unroll
      for (int h = 0; h < 2; ++h) {
        s16x8 bf = *(const s16x8*)(wb + (size_t)(128 * j + 64 * h) * 64);
#pragma unroll
        for (int mi = 0; mi < 2; ++mi)
          acc2[mi][j][h] = __builtin_amdgcn_mfma_f32_16x16x32_bf16(a[mi], bf, acc2[mi][j][h], 0, 0, 0);
      }
    }
  }

  // ---- Phase 3: LSTM pointwise + mask select. acc2[mi][j][h]: gate j (i,f,g,o), d = 16w+64h+l15
  float bs[4][2];
#pragma unroll
  for (int j = 0; j < 4; ++j)
#pragma unroll
    for (int h = 0; h < 2; ++h) bs[j][h] = biasg[128 * j + 64 * h + 16 * w + l15];

#pragma unroll
  for (int mi = 0; mi < 2; ++mi) {
#pragma unroll
    for (int r = 0; r < 4; ++r) {
      int m = mi * 16 + lk * 4 + r;
      size_t node = (size_t)node0 + m;
      int act = tsm[node];
#pragma unroll
      for (int h = 0; h < 2; ++h) {
        int d = 16 * w + 64 * h + l15;
        float gi = acc2[mi][0][h][r] + bs[0][h];
        float gf = acc2[mi][1][h][r] + bs[1][h];
        float gg = acc2[mi][2][h][r] + bs[2][h];
        float go = acc2[mi][3][h][r] + bs[3][h];
        float i_ = fsig(gi), f_ = fsig(gf), o_ = fsig(go);
        float g_ = ftanh(gg);
        float co = cvp[node * 128 + d];
        float ho = hvp[node * 128 + d];
        float cn = f_ * co + i_ * g_;
        float hn = o_ * ftanh(cn);
        hvo[node * 128 + d] = act ? hn : ho;
        cvo[node * 128 + d] = act ? cn : co;
      }
    }
  }
}

extern "C" void kernel_launch(void* const* d_in, const int* in_sizes, int n_in,
                              void* d_out, int out_size, void* d_ws, size_t ws_size,
                              hipStream_t stream) {
  const float* Hv   = (const float*)d_in[0];
  const float* hvv  = (const float*)d_in[1];
  const float* xv   = (const float*)d_in[2];
  const float* hvp  = (const float*)d_in[3];
  const float* cvp  = (const float*)d_in[4];
  const int*   tsm  = (const int*)d_in[5];
  const float* Wpos = (const float*)d_in[6];
  const float* bpos = (const float*)d_in[7];
  const float* Whid = (const float*)d_in[8];
  const float* bhid = (const float*)d_in[9];
  const float* Wih  = (const float*)d_in[10];
  const float* bih  = (const float*)d_in[11];
  const float* Whh  = (const float*)d_in[12];
  const float* bhh  = (const float*)d_in[13];

  unsigned short* wsWh2 = (unsigned short*)d_ws;   // 32768 bf16
  unsigned short* wsW2  = wsWh2 + 32768;           // 131072 bf16
  float* wsBias = (float*)(wsW2 + 131072);         // 512 f32

  prep_kernel<<<512, 256, 0, stream>>>(Whid, Wih, Whh, bih, bhh,
                                       wsWh2, wsW2, wsBias);

  float* hvo = (float*)d_out;
  float* cvo = hvo + (size_t)N_NODES * 128;
  node_rnn_kernel<<<N_NODES / BM, NTHREADS, 0, stream>>>(
      Hv, hvv, xv, hvp, cvp, tsm, Wpos, bpos, bhid,
      wsWh2, wsW2, wsBias, hvo, cvo);
}